// Round 1
// baseline (320.896 us; speedup 1.0000x reference)
//
#include <hip/hip_runtime.h>

#define BB 256
#define DD 256
#define KK 1024
#define EE 16
#define DECAY 0.999f
#define GAIN  0.001f
#define EPS   1e-6f

// output offsets in floats (tuple order: cw_embed, one_hot, new_codebook, new_ema)
#define OH_OFF   ((size_t)BB * DD * EE)                    // 1048576
#define CB_OFF   (OH_OFF + (size_t)BB * DD * KK)           // 68157440
#define EMA_OFF  (CB_OFF + (size_t)DD * KK * EE)           // 72351744

__device__ __forceinline__ float dot16(const float4& a0, const float4& a1,
                                       const float4& a2, const float4& a3,
                                       const float4& b0, const float4& b1,
                                       const float4& b2, const float4& b3) {
  float s = a0.x * b0.x;
  s = fmaf(a0.y, b0.y, s); s = fmaf(a0.z, b0.z, s); s = fmaf(a0.w, b0.w, s);
  s = fmaf(a1.x, b1.x, s); s = fmaf(a1.y, b1.y, s); s = fmaf(a1.z, b1.z, s); s = fmaf(a1.w, b1.w, s);
  s = fmaf(a2.x, b2.x, s); s = fmaf(a2.y, b2.y, s); s = fmaf(a2.z, b2.z, s); s = fmaf(a2.w, b2.w, s);
  s = fmaf(a3.x, b3.x, s); s = fmaf(a3.y, b3.y, s); s = fmaf(a3.z, b3.z, s); s = fmaf(a3.w, b3.w, s);
  return s;
}

__global__ __launch_bounds__(256) void vqvae_fused(
    const float* __restrict__ cw_q,      // (B, D*E)
    const float* __restrict__ codebook,  // (D, K, E)
    const float* __restrict__ ema,       // (D, K)
    float* __restrict__ out)             // concatenated outputs
{
  __shared__ float4 cb4s[KK * EE / 4];   // 64 KB  codebook row d
  __shared__ float4 upd4s[KK * EE / 4];  // 64 KB  update accumulator
  __shared__ float  c2s[KK];             // 4 KB   |c|^2 (reused as ema_sh)
  __shared__ float  cnts[KK];            // 4 KB   counts
  __shared__ float  pbest[2 * BB];       // partial argmin (dist)
  __shared__ int    pidx[2 * BB];        // partial argmin (idx)

  float* upd = (float*)upd4s;

  const int t = threadIdx.x;
  const int d = blockIdx.x;
  const float4 z4 = make_float4(0.f, 0.f, 0.f, 0.f);

  // ---- phase 0a: zero LDS accumulators ----
  #pragma unroll
  for (int j = 0; j < 4; ++j) { c2s[t + 256 * j] = 0.f; cnts[t + 256 * j] = 0.f; }
  #pragma unroll
  for (int i = 0; i < 16; ++i) upd4s[i * 256 + t] = z4;
  __syncthreads();

  // ---- phase 0b: stage codebook row d -> LDS, accumulate c2 ----
  const float4* src4 = (const float4*)codebook + (size_t)d * (KK * EE / 4);
  #pragma unroll
  for (int i = 0; i < 16; ++i) {
    int idx4 = i * 256 + t;
    float4 v = src4[idx4];
    cb4s[idx4] = v;
    float sq = fmaf(v.x, v.x, 0.f);
    sq = fmaf(v.y, v.y, sq); sq = fmaf(v.z, v.z, sq); sq = fmaf(v.w, v.w, sq);
    atomicAdd(&c2s[idx4 >> 2], sq);
  }
  __syncthreads();

  // ---- phase 1: distances + argmin, with interleaved one_hot zero-fill ----
  // thread t handles b0=2*(t&127), b1=b0+1 over k in [h*512, h*512+512)
  const int h  = t >> 7;
  const int b0 = (t & 127) << 1;
  const int b1 = b0 + 1;

  const float4* xr0 = (const float4*)cw_q + (size_t)b0 * (DD * EE / 4) + d * 4;
  const float4* xr1 = (const float4*)cw_q + (size_t)b1 * (DD * EE / 4) + d * 4;
  float4 xa0 = xr0[0], xb0 = xr0[1], xc0 = xr0[2], xd0 = xr0[3];
  float4 xa1 = xr1[0], xb1 = xr1[1], xc1 = xr1[2], xd1 = xr1[3];
  const float x2_0 = dot16(xa0, xb0, xc0, xd0, xa0, xb0, xc0, xd0);
  const float x2_1 = dot16(xa1, xb1, xc1, xd1, xa1, xb1, xc1, xd1);

  float best0 = 3.4e38f, best1 = 3.4e38f;
  int   bi0 = 0, bi1 = 0;
  const int kbase = h << 9;

  float* ohp = out + OH_OFF;
  const int w = t >> 6;      // wave id: owns one_hot rows [64w, 64w+64)
  const int l = t & 63;

  for (int s = 0; s < 256; ++s) {
    const int k0 = kbase + (s << 1);
    const int k1 = k0 + 1;
    const float4* p = cb4s + (k0 << 2);   // broadcast LDS reads
    float4 ca0 = p[0], ca1 = p[1], ca2 = p[2], ca3 = p[3];
    float4 cb0 = p[4], cb1 = p[5], cb2 = p[6], cb3 = p[7];

    float dot00 = dot16(ca0, ca1, ca2, ca3, xa0, xb0, xc0, xd0);
    float dot01 = dot16(ca0, ca1, ca2, ca3, xa1, xb1, xc1, xd1);
    float dot10 = dot16(cb0, cb1, cb2, cb3, xa0, xb0, xc0, xd0);
    float dot11 = dot16(cb0, cb1, cb2, cb3, xa1, xb1, xc1, xd1);

    const float c2k0 = c2s[k0], c2k1 = c2s[k1];
    float d00 = (x2_0 + c2k0) - 2.f * dot00;
    if (d00 < best0) { best0 = d00; bi0 = k0; }
    float d01 = (x2_1 + c2k0) - 2.f * dot01;
    if (d01 < best1) { best1 = d01; bi1 = k0; }
    float d10 = (x2_0 + c2k1) - 2.f * dot10;
    if (d10 < best0) { best0 = d10; bi0 = k1; }
    float d11 = (x2_1 + c2k1) - 2.f * dot11;
    if (d11 < best1) { best1 = d11; bi1 = k1; }

    // interleaved one_hot zero-fill: wave w writes row b=(64w + s/4), quarter s%4
    const int brow = (w << 6) + (s >> 2);
    const int q = s & 3;
    float4* dst = (float4*)(ohp + (size_t)brow * (DD * KK) + (size_t)d * KK + q * 256);
    dst[l] = z4;
  }

  pbest[(h << 8) + b0] = best0;  pidx[(h << 8) + b0] = bi0;
  pbest[(h << 8) + b1] = best1;  pidx[(h << 8) + b1] = bi1;
  __syncthreads();   // drains zero-stores (vmcnt) + pbest/pidx (lgkmcnt)

  // ---- phase 2: merge halves, write cw_embed + one_hot 1.0, accumulate update ----
  {
    const int b = t;
    float e0 = pbest[b];        int i0 = pidx[b];
    float e1 = pbest[256 + b];  int i1 = pidx[256 + b];
    const int bidx = (e1 < e0) ? i1 : i0;   // tie -> lower-k half, matches np.argmin

    float4* ce = (float4*)out + (size_t)b * (DD * EE / 4) + d * 4;
    const float4* cw = cb4s + (bidx << 2);
    ce[0] = cw[0]; ce[1] = cw[1]; ce[2] = cw[2]; ce[3] = cw[3];

    ohp[(size_t)b * (DD * KK) + (size_t)d * KK + bidx] = 1.0f;

    atomicAdd(&cnts[bidx], 1.0f);
    const float* xrow = cw_q + (size_t)b * (DD * EE) + (size_t)d * EE;
    #pragma unroll
    for (int e = 0; e < 16; ++e) atomicAdd(&upd[(bidx << 4) + e], xrow[e]);
  }
  __syncthreads();

  // ---- phase 3a: new_ema + stage ema into LDS (reuse c2s) ----
  float* ema_sh = c2s;
  const float* emad   = ema + (size_t)d * KK;
  float* out_ema      = out + EMA_OFF + (size_t)d * KK;
  #pragma unroll
  for (int j = 0; j < 4; ++j) {
    int k = t + 256 * j;
    float ev = emad[k];
    ema_sh[k] = ev;
    out_ema[k] = DECAY * ev + GAIN * cnts[k];
  }
  __syncthreads();

  // ---- phase 3b: new_codebook ----
  float4* out_cb4 = (float4*)(out + CB_OFF) + (size_t)d * (KK * EE / 4);
  #pragma unroll
  for (int i = 0; i < 16; ++i) {
    int idx4 = i * 256 + t;
    int k = idx4 >> 2;
    float4 c = cb4s[idx4];
    float4 u = upd4s[idx4];
    float inv = GAIN / (ema_sh[k] + EPS);
    float4 r;
    r.x = DECAY * c.x + u.x * inv;
    r.y = DECAY * c.y + u.y * inv;
    r.z = DECAY * c.z + u.z * inv;
    r.w = DECAY * c.w + u.w * inv;
    out_cb4[idx4] = r;
  }
}

extern "C" void kernel_launch(void* const* d_in, const int* in_sizes, int n_in,
                              void* d_out, int out_size, void* d_ws, size_t ws_size,
                              hipStream_t stream) {
  const float* cw_q     = (const float*)d_in[0];
  const float* codebook = (const float*)d_in[1];
  const float* ema      = (const float*)d_in[2];
  float* out = (float*)d_out;
  (void)in_sizes; (void)n_in; (void)out_size; (void)d_ws; (void)ws_size;
  vqvae_fused<<<dim3(DD), dim3(256), 0, stream>>>(cw_q, codebook, ema, out);
}